// Round 16
// baseline (235.644 us; speedup 1.0000x reference)
//
#include <hip/hip_runtime.h>
#include <hip/hip_bf16.h>
#include <cstdint>

#define D_MODEL 2048
#define N_BATCH 16384

typedef __attribute__((ext_vector_type(8))) __bf16 bf16x8;
typedef __attribute__((ext_vector_type(4))) float f32x4;

__device__ __forceinline__ unsigned short f2bf(float f) {
    unsigned int u = __builtin_bit_cast(unsigned int, f);
    u += 0x7fffu + ((u >> 16) & 1u);
    return (unsigned short)(u >> 16);
}

// ==== K1: fused prep = transpose(w_v) || (convert(w_o) + bias dot, one pass) ====
__global__ __launch_bounds__(256) void prep_kernel(
    const float* __restrict__ w_v, const float* __restrict__ w_o,
    const float* __restrict__ b_v, const float* __restrict__ b_o,
    unsigned short* __restrict__ wvT, unsigned short* __restrict__ woB,
    float* __restrict__ b_c)
{
    __shared__ float tile[32][33];
    const int b = blockIdx.x;
    const int t = threadIdx.x;
    if (b < 4096) {
        const int nb = 64;
        const int k0 = (b % nb) * 32;
        const int j0 = (b / nb) * 32;
        const int tx = t & 31, ty0 = t >> 5;
        #pragma unroll
        for (int i = 0; i < 32; i += 8) {
            int j = ty0 + i;
            tile[j][tx] = w_v[(long)(j0 + j) * D_MODEL + k0 + tx];
        }
        __syncthreads();
        #pragma unroll
        for (int i = 0; i < 32; i += 8) {
            int kk = ty0 + i;
            wvT[(long)(k0 + kk) * D_MODEL + j0 + tx] = f2bf(tile[tx][kk]);
        }
    } else {
        const int n = b - 4096;
        const float4* w4 = reinterpret_cast<const float4*>(w_o + (long)n * D_MODEL);
        const float4* v4 = reinterpret_cast<const float4*>(b_v);
        float4 a = w4[t], bb = w4[256 + t], va = v4[t], vb = v4[256 + t];
        unsigned short* orow = woB + (long)n * D_MODEL;
        {
            ushort4 o;
            o.x = f2bf(a.x); o.y = f2bf(a.y); o.z = f2bf(a.z); o.w = f2bf(a.w);
            *reinterpret_cast<ushort4*>(orow + t * 4) = o;
        }
        {
            ushort4 o;
            o.x = f2bf(bb.x); o.y = f2bf(bb.y); o.z = f2bf(bb.z); o.w = f2bf(bb.w);
            *reinterpret_cast<ushort4*>(orow + 1024 + t * 4) = o;
        }
        float s = a.x*va.x + a.y*va.y + a.z*va.z + a.w*va.w
                + bb.x*vb.x + bb.y*vb.y + bb.z*vb.z + bb.w*vb.w;
        #pragma unroll
        for (int off = 32; off; off >>= 1) s += __shfl_xor(s, off);
        float* red = &tile[0][0];
        const int lane = t & 63, wid = t >> 6;
        if (lane == 0) red[wid] = s;
        __syncthreads();
        if (t == 0) b_c[n] = red[0] + red[1] + red[2] + red[3] + b_o[n];
    }
}

// ============ K2: fused Wc-GEMM (128-tile m97) || LayerNorm ============
__global__ __launch_bounds__(256) void lnwc_kernel(
    const unsigned short* __restrict__ A, const unsigned short* __restrict__ B,
    unsigned short* __restrict__ C,
    const float* __restrict__ x, const float* __restrict__ gamma,
    const float* __restrict__ beta, unsigned short* __restrict__ h)
{
    __shared__ __align__(16) unsigned short Alds[128 * 32];
    __shared__ __align__(16) unsigned short Blds[128 * 32];
    const int t = threadIdx.x;

    if (blockIdx.x < 256) {
        const int K = D_MODEL, N = D_MODEL;
        int wg = blockIdx.x;
        wg = (wg & 7) * 32 + (wg >> 3);         // XCD swizzle, cpx = 32
        const int bm = wg >> 4, bn = wg & 15;

        const int lane = t & 63, wid = t >> 6;
        const int wr = wid >> 1, wc = wid & 1;

        f32x4 acc[4][4];
        #pragma unroll
        for (int i = 0; i < 4; i++)
            #pragma unroll
            for (int j = 0; j < 4; j++) acc[i][j] = (f32x4){0.f, 0.f, 0.f, 0.f};

        const long Abase = (long)bm * 128 * K;
        const long Bbase = (long)bn * 128 * K;
        const int ci0 = wid * 64 + lane;
        const int ci1 = 256 + ci0;
        const int r0 = ci0 >> 2, c0 = (ci0 & 3) * 8;
        const int r1 = ci1 >> 2, c1 = (ci1 & 3) * 8;

        const int arow = wr * 64 + (lane & 15);
        const int brow = wc * 64 + (lane & 15);
        const int koff = (lane >> 4) * 8;

        for (int k0 = 0; k0 < K; k0 += 32) {
            __builtin_amdgcn_global_load_lds(
                (const __attribute__((address_space(1))) void*)(A + Abase + (long)r0 * K + k0 + c0),
                (__attribute__((address_space(3))) void*)(Alds + wid * 512), 16, 0, 0);
            __builtin_amdgcn_global_load_lds(
                (const __attribute__((address_space(1))) void*)(A + Abase + (long)r1 * K + k0 + c1),
                (__attribute__((address_space(3))) void*)(Alds + 2048 + wid * 512), 16, 0, 0);
            __builtin_amdgcn_global_load_lds(
                (const __attribute__((address_space(1))) void*)(B + Bbase + (long)r0 * K + k0 + c0),
                (__attribute__((address_space(3))) void*)(Blds + wid * 512), 16, 0, 0);
            __builtin_amdgcn_global_load_lds(
                (const __attribute__((address_space(1))) void*)(B + Bbase + (long)r1 * K + k0 + c1),
                (__attribute__((address_space(3))) void*)(Blds + 2048 + wid * 512), 16, 0, 0);
            __syncthreads();

            bf16x8 af[4], bfr[4];
            #pragma unroll
            for (int m = 0; m < 4; m++)
                af[m] = *reinterpret_cast<const bf16x8*>(&Alds[(arow + m * 16) * 32 + koff]);
            #pragma unroll
            for (int n = 0; n < 4; n++)
                bfr[n] = *reinterpret_cast<const bf16x8*>(&Blds[(brow + n * 16) * 32 + koff]);
            #pragma unroll
            for (int m = 0; m < 4; m++)
                #pragma unroll
                for (int n = 0; n < 4; n++)
                    acc[m][n] = __builtin_amdgcn_mfma_f32_16x16x32_bf16(af[m], bfr[n], acc[m][n], 0, 0, 0);
            __syncthreads();
        }

        const int crow0 = bm * 128 + wr * 64 + ((lane >> 4) << 2);
        const int ccol0 = bn * 128 + wc * 64 + (lane & 15);
        #pragma unroll
        for (int m = 0; m < 4; m++)
            #pragma unroll
            for (int j = 0; j < 4; j++) {
                const long r = crow0 + m * 16 + j;
                #pragma unroll
                for (int n = 0; n < 4; n++)
                    C[r * N + ccol0 + n * 16] = f2bf(acc[m][n][j]);
            }
    } else {
        const int row = blockIdx.x - 256;
        const float4* x4 = reinterpret_cast<const float4*>(x + (long)row * D_MODEL);
        float4 a = x4[t];
        float4 b = x4[256 + t];
        float s  = a.x + a.y + a.z + a.w + b.x + b.y + b.z + b.w;
        float ss = a.x*a.x + a.y*a.y + a.z*a.z + a.w*a.w
                 + b.x*b.x + b.y*b.y + b.z*b.z + b.w*b.w;
        #pragma unroll
        for (int off = 32; off; off >>= 1) {
            s  += __shfl_xor(s, off);
            ss += __shfl_xor(ss, off);
        }
        float* red = reinterpret_cast<float*>(Alds);
        const int lane = t & 63, wid = t >> 6;
        if (lane == 0) { red[wid*2] = s; red[wid*2+1] = ss; }
        __syncthreads();
        s  = red[0] + red[2] + red[4] + red[6];
        ss = red[1] + red[3] + red[5] + red[7];
        const float mean = s * (1.0f / D_MODEL);
        const float var  = ss * (1.0f / D_MODEL) - mean * mean;
        const float inv  = rsqrtf(var + 1e-5f);

        const float4* g4  = reinterpret_cast<const float4*>(gamma);
        const float4* be4 = reinterpret_cast<const float4*>(beta);
        ushort4* h4 = reinterpret_cast<ushort4*>(h + (long)row * D_MODEL);
        {
            float4 g = g4[t], be = be4[t];
            ushort4 o;
            o.x = f2bf((a.x - mean) * inv * g.x + be.x);
            o.y = f2bf((a.y - mean) * inv * g.y + be.y);
            o.z = f2bf((a.z - mean) * inv * g.z + be.z);
            o.w = f2bf((a.w - mean) * inv * g.w + be.w);
            h4[t] = o;
        }
        {
            float4 g = g4[256 + t], be = be4[256 + t];
            ushort4 o;
            o.x = f2bf((b.x - mean) * inv * g.x + be.x);
            o.y = f2bf((b.y - mean) * inv * g.y + be.y);
            o.z = f2bf((b.z - mean) * inv * g.z + be.z);
            o.w = f2bf((b.w - mean) * inv * g.w + be.w);
            h4[256 + t] = o;
        }
    }
}

// ======== K3: persistent 2-tile BT-GEMM, 256x256 8-phase (r15 K-loop) ========
// C[m][n] = sum_k A[m][k]*B[n][k] + bias[n] + resid[m][n], fp32 out.
// Grid 256 (1 block/CU): each block does tiles wgs and wgs+256 (same bn ->
// B-panel L2-hot for tile 1; bm differs by 32).  Tile-1's 12 prologue loads
// are issued BEFORE tile-0's epilogue -> the ~64 epilogue memory ops hide the
// prologue HBM latency; no inter-round dispatch bubble.  Tile-1's first
// vmcnt(4) also counts trailing epilogue ops -> strictly MORE conservative
// than r15's invariant (all prologue loads retired before the barrier).
// K-loop = r15's proven relaxed 8-phase (setprio dropped: m190 shows it's
// null-to-negative on GEMM without the strict phase structure).
#define GLL(src, dst) __builtin_amdgcn_global_load_lds( \
    (const __attribute__((address_space(1))) void*)(src), \
    (__attribute__((address_space(3))) void*)(dst), 16, 0, 0)
#define WAITV4() do { asm volatile("s_waitcnt vmcnt(4)" ::: "memory"); \
                      __builtin_amdgcn_sched_barrier(0); } while (0)
#define WAITV0() do { asm volatile("s_waitcnt vmcnt(0)" ::: "memory"); \
                      __builtin_amdgcn_sched_barrier(0); } while (0)

__global__ __launch_bounds__(512, 2) void gemm_bt_8ph(
    const unsigned short* __restrict__ A, const unsigned short* __restrict__ B,
    float* __restrict__ C, const float* __restrict__ bias,
    const float* __restrict__ resid, int M, int N, int K)
{
    __shared__ __align__(16) char ldsb[131072];

    const int t = threadIdx.x;
    const int lane = t & 63, wid = t >> 6;
    const int wr = wid >> 2;            // 0..1
    const int wc = wid & 3;             // 0..3

    const long Kl = K;
    const int tr = t >> 3;
    const int c8 = ((t & 7) ^ (tr & 7)) * 8;

    const int l15 = lane & 15, l4 = lane >> 4;
    const int swz0 = ((l4)     ^ (l15 & 7)) << 4;
    const int swz1 = ((4 + l4) ^ (l15 & 7)) << 4;
    const int aOff = wr * 16384 + l15 * 128;
    const int bOff = 32768 + (wc >> 1) * 16384 + ((wc & 1) * 64 + l15) * 128;

    // wgs for tile 0; tile 1 = wgs + 256 (same bn, bm+32)
    const int wgs = (blockIdx.x & 7) * 32 + (blockIdx.x >> 3);

#define ST_A(P, buf, half, kcol) do { \
    const unsigned short* s_ = (P) + (half) * 128 * Kl + (kcol); \
    char* d_ = ldsb + (buf) * 65536 + (half) * 16384 + t * 16; \
    GLL(s_, d_); GLL(s_ + 64 * Kl, d_ + 8192); } while (0)
#define ST_B(P, buf, half, kcol) do { \
    const unsigned short* s_ = (P) + (half) * 128 * Kl + (kcol); \
    char* d_ = ldsb + (buf) * 65536 + 32768 + (half) * 16384 + t * 16; \
    GLL(s_, d_); GLL(s_ + 64 * Kl, d_ + 8192); } while (0)

#define LDV(off) (*reinterpret_cast<const bf16x8*>(ldsb + (off)))
#define RD_A(buf, mh) do { \
    _Pragma("unroll") for (int mi = 0; mi < 4; ++mi) \
        af[mi][0] = LDV((buf) * 65536 + aOff + ((mh) * 4 + mi) * 2048 + swz0); \
    _Pragma("unroll") for (int mi = 0; mi < 4; ++mi) \
        af[mi][1] = LDV((buf) * 65536 + aOff + ((mh) * 4 + mi) * 2048 + swz1); } while (0)
#define RD_B0(buf) do { \
    _Pragma("unroll") for (int nj = 0; nj < 2; ++nj) \
        b0[nj][0] = LDV((buf) * 65536 + bOff + nj * 2048 + swz0); \
    _Pragma("unroll") for (int nj = 0; nj < 2; ++nj) \
        b0[nj][1] = LDV((buf) * 65536 + bOff + nj * 2048 + swz1); } while (0)
#define RD_B1(buf) do { \
    _Pragma("unroll") for (int nj = 0; nj < 2; ++nj) \
        b1[nj][0] = LDV((buf) * 65536 + bOff + (2 + nj) * 2048 + swz0); \
    _Pragma("unroll") for (int nj = 0; nj < 2; ++nj) \
        b1[nj][1] = LDV((buf) * 65536 + bOff + (2 + nj) * 2048 + swz1); } while (0)

#define MMQ(mh, nh, BQ) do { \
    _Pragma("unroll") for (int kk = 0; kk < 2; ++kk) \
    _Pragma("unroll") for (int mi = 0; mi < 4; ++mi) \
    _Pragma("unroll") for (int nj = 0; nj < 2; ++nj) \
        acc[(mh) * 4 + mi][(nh) * 2 + nj] = __builtin_amdgcn_mfma_f32_16x16x32_bf16( \
            af[mi][kk], BQ[nj][kk], acc[(mh) * 4 + mi][(nh) * 2 + nj], 0, 0, 0); \
    } while (0)
#define ENDP() __builtin_amdgcn_s_barrier()

    bf16x8 af[4][2], b0[2][2], b1[2][2];
    f32x4 acc[8][4];
    const int NI = K >> 7;              // 16 iterations, 2 K-tiles each

    // prologue for tile 0
    {
        const int bm0 = wgs >> 3, bn0 = wgs & 7;
        const unsigned short* As = A + (long)(bm0 * 256 + tr) * Kl + c8;
        const unsigned short* Bs = B + (long)(bn0 * 256 + tr) * Kl + c8;
        ST_A(As, 0, 0, 0); ST_A(As, 0, 1, 0); ST_B(Bs, 0, 0, 0); ST_B(Bs, 0, 1, 0);
        ST_B(Bs, 1, 0, 64); ST_A(As, 1, 0, 64);
    }

    #pragma unroll 1
    for (int tile = 0; tile < 2; ++tile) {
        const int wg = wgs + tile * 256;
        const int bm = wg >> 3, bn = wg & 7;
        const unsigned short* As = A + (long)(bm * 256 + tr) * Kl + c8;
        const unsigned short* Bs = B + (long)(bn * 256 + tr) * Kl + c8;

        #pragma unroll
        for (int i = 0; i < 8; i++)
            #pragma unroll
            for (int j = 0; j < 4; j++) acc[i][j] = (f32x4){0.f, 0.f, 0.f, 0.f};

        WAITV4();                       // prologue loads retired (see header)
        __builtin_amdgcn_s_barrier();

        for (int i = 0; i < NI; ++i) {
            const int kcA1 = (i << 7) + 64;
            const int kcN0 = (i << 7) + 128;
            const int kcN1 = (i << 7) + 192;
            const bool more = (i + 1 < NI);

            RD_A(0, 0); RD_B0(0);
            ST_A(As, 1, 1, kcA1);
            MMQ(0, 0, b0); ENDP();

            RD_B1(0);
            ST_B(Bs, 1, 1, kcA1);
            MMQ(0, 1, b1); ENDP();

            RD_A(0, 1);
            if (more) ST_B(Bs, 0, 0, kcN0);
            MMQ(1, 0, b0); ENDP();

            if (more) ST_A(As, 0, 0, kcN0);
            MMQ(1, 1, b1);
            if (more) { WAITV4(); } else { WAITV0(); }
            ENDP();

            RD_A(1, 0); RD_B0(1);
            if (more) ST_A(As, 0, 1, kcN0);
            MMQ(0, 0, b0); ENDP();

            RD_B1(1);
            if (more) ST_B(Bs, 0, 1, kcN0);
            MMQ(0, 1, b1); ENDP();

            RD_A(1, 1);
            if (more) ST_B(Bs, 1, 0, kcN1);
            MMQ(1, 0, b0); ENDP();

            if (more) ST_A(As, 1, 0, kcN1);
            MMQ(1, 1, b1);
            if (more) { WAITV4(); }
            ENDP();
        }

        // issue tile-1 prologue BEFORE the epilogue (overlap with its mem ops)
        if (tile == 0) {
            const int wg1 = wgs + 256;
            const int bm1 = wg1 >> 3, bn1 = wg1 & 7;
            const unsigned short* As1 = A + (long)(bm1 * 256 + tr) * Kl + c8;
            const unsigned short* Bs1 = B + (long)(bn1 * 256 + tr) * Kl + c8;
            ST_A(As1, 0, 0, 0); ST_A(As1, 0, 1, 0);
            ST_B(Bs1, 0, 0, 0); ST_B(Bs1, 0, 1, 0);
            ST_B(Bs1, 1, 0, 64); ST_A(As1, 1, 0, 64);
        }

        // epilogue: direct coalesced-segment stores (r9-proven)
        {
            const int crow0 = bm * 256 + wr * 128 + l4 * 4;
            const int ccol0 = bn * 256 + wc * 64 + l15;
            float bias4[4];
            #pragma unroll
            for (int n = 0; n < 4; n++) bias4[n] = bias[ccol0 + n * 16];
            #pragma unroll
            for (int m = 0; m < 8; m++)
                #pragma unroll
                for (int j = 0; j < 4; j++) {
                    const long r = crow0 + m * 16 + j;
                    float* crow = C + r * N;
                    const float* rrow = resid + r * N;
                    #pragma unroll
                    for (int n = 0; n < 4; n++) {
                        const int col = ccol0 + n * 16;
                        crow[col] = acc[m][n][j] + bias4[n] + rrow[col];
                    }
                }
        }
    }
#undef ST_A
#undef ST_B
#undef RD_A
#undef RD_B0
#undef RD_B1
#undef MMQ
#undef ENDP
#undef LDV
}

extern "C" void kernel_launch(void* const* d_in, const int* in_sizes, int n_in,
                              void* d_out, int out_size, void* d_ws, size_t ws_size,
                              hipStream_t stream) {
    // setup_inputs order: x, w_q, b_q, w_k, b_k, w_v, b_v, w_o, b_o, ln_gamma, ln_beta
    const float* x     = (const float*)d_in[0];
    const float* w_v   = (const float*)d_in[5];
    const float* b_v   = (const float*)d_in[6];
    const float* w_o   = (const float*)d_in[7];
    const float* b_o   = (const float*)d_in[8];
    const float* gamma = (const float*)d_in[9];
    const float* beta  = (const float*)d_in[10];
    float* out = (float*)d_out;

    char* ws = (char*)d_ws;
    unsigned short* h   = (unsigned short*)(ws);                              // 64 MiB
    unsigned short* wvT = (unsigned short*)(ws + 67108864L);                  // 8 MiB
    unsigned short* woB = (unsigned short*)(ws + 67108864L + 8388608L);       // 8 MiB
    unsigned short* Wc  = (unsigned short*)(ws + 67108864L + 2 * 8388608L);   // 8 MiB
    float*          b_c = (float*)(ws + 67108864L + 3 * 8388608L);            // 8 KiB

    // K1: transpose(w_v) || {convert(w_o) + bias dot, single w_o pass}
    prep_kernel<<<6144, 256, 0, stream>>>(w_v, w_o, b_v, b_o, wvT, woB, b_c);
    // K2: Wc = woB . wvT^T (blocks 0-255) || h = LN(x) (blocks 256+)
    lnwc_kernel<<<256 + N_BATCH, 256, 0, stream>>>(woB, wvT, Wc, x, gamma, beta, h);
    // K3: out = h . Wc^T + b_c + x  (persistent, 2 tiles/block)
    gemm_bt_8ph<<<256, 512, 0, stream>>>(
        h, Wc, out, b_c, x, N_BATCH, D_MODEL, D_MODEL);
}

// Round 17
// 221.501 us; speedup vs baseline: 1.0639x; 1.0639x over previous
//
#include <hip/hip_runtime.h>
#include <hip/hip_bf16.h>
#include <cstdint>

#define D_MODEL 2048
#define N_BATCH 16384

typedef __attribute__((ext_vector_type(8))) __bf16 bf16x8;
typedef __attribute__((ext_vector_type(4))) float f32x4;

__device__ __forceinline__ unsigned short f2bf(float f) {
    unsigned int u = __builtin_bit_cast(unsigned int, f);
    u += 0x7fffu + ((u >> 16) & 1u);
    return (unsigned short)(u >> 16);
}

// ==== K1: fused prep = transpose(w_v) || (convert(w_o) + bias dot, one pass) ====
// blocks [0,4096): wvT[k][j] = bf16(w_v[j][k])
// blocks [4096,6144): row n = b-4096: woB[n][:] = bf16(w_o[n][:]) AND
//                     b_c[n] = b_o[n] + w_o[n][:] . b_v   (w_o read ONCE)
__global__ __launch_bounds__(256) void prep_kernel(
    const float* __restrict__ w_v, const float* __restrict__ w_o,
    const float* __restrict__ b_v, const float* __restrict__ b_o,
    unsigned short* __restrict__ wvT, unsigned short* __restrict__ woB,
    float* __restrict__ b_c)
{
    __shared__ float tile[32][33];
    const int b = blockIdx.x;
    const int t = threadIdx.x;
    if (b < 4096) {
        const int nb = 64;
        const int k0 = (b % nb) * 32;
        const int j0 = (b / nb) * 32;
        const int tx = t & 31, ty0 = t >> 5;
        #pragma unroll
        for (int i = 0; i < 32; i += 8) {
            int j = ty0 + i;
            tile[j][tx] = w_v[(long)(j0 + j) * D_MODEL + k0 + tx];
        }
        __syncthreads();
        #pragma unroll
        for (int i = 0; i < 32; i += 8) {
            int kk = ty0 + i;
            wvT[(long)(k0 + kk) * D_MODEL + j0 + tx] = f2bf(tile[tx][kk]);
        }
    } else {
        const int n = b - 4096;
        const float4* w4 = reinterpret_cast<const float4*>(w_o + (long)n * D_MODEL);
        const float4* v4 = reinterpret_cast<const float4*>(b_v);
        float4 a = w4[t], bb = w4[256 + t], va = v4[t], vb = v4[256 + t];
        // bf16 convert + store (row n, elements 4t..4t+3 and 1024+4t..)
        unsigned short* orow = woB + (long)n * D_MODEL;
        {
            ushort4 o;
            o.x = f2bf(a.x); o.y = f2bf(a.y); o.z = f2bf(a.z); o.w = f2bf(a.w);
            *reinterpret_cast<ushort4*>(orow + t * 4) = o;
        }
        {
            ushort4 o;
            o.x = f2bf(bb.x); o.y = f2bf(bb.y); o.z = f2bf(bb.z); o.w = f2bf(bb.w);
            *reinterpret_cast<ushort4*>(orow + 1024 + t * 4) = o;
        }
        // bias dot (same registers, no second read)
        float s = a.x*va.x + a.y*va.y + a.z*va.z + a.w*va.w
                + bb.x*vb.x + bb.y*vb.y + bb.z*vb.z + bb.w*vb.w;
        #pragma unroll
        for (int off = 32; off; off >>= 1) s += __shfl_xor(s, off);
        float* red = &tile[0][0];
        const int lane = t & 63, wid = t >> 6;
        if (lane == 0) red[wid] = s;
        __syncthreads();
        if (t == 0) b_c[n] = red[0] + red[1] + red[2] + red[3] + b_o[n];
    }
}

// ============ K2: fused Wc-GEMM (128-tile m97) || LayerNorm ============
__global__ __launch_bounds__(256) void lnwc_kernel(
    const unsigned short* __restrict__ A, const unsigned short* __restrict__ B,
    unsigned short* __restrict__ C,
    const float* __restrict__ x, const float* __restrict__ gamma,
    const float* __restrict__ beta, unsigned short* __restrict__ h)
{
    __shared__ __align__(16) unsigned short Alds[128 * 32];
    __shared__ __align__(16) unsigned short Blds[128 * 32];
    const int t = threadIdx.x;

    if (blockIdx.x < 256) {
        const int K = D_MODEL, N = D_MODEL;
        int wg = blockIdx.x;
        wg = (wg & 7) * 32 + (wg >> 3);         // XCD swizzle, cpx = 32
        const int bm = wg >> 4, bn = wg & 15;

        const int lane = t & 63, wid = t >> 6;
        const int wr = wid >> 1, wc = wid & 1;

        f32x4 acc[4][4];
        #pragma unroll
        for (int i = 0; i < 4; i++)
            #pragma unroll
            for (int j = 0; j < 4; j++) acc[i][j] = (f32x4){0.f, 0.f, 0.f, 0.f};

        const long Abase = (long)bm * 128 * K;
        const long Bbase = (long)bn * 128 * K;
        const int ci0 = wid * 64 + lane;
        const int ci1 = 256 + ci0;
        const int r0 = ci0 >> 2, c0 = (ci0 & 3) * 8;
        const int r1 = ci1 >> 2, c1 = (ci1 & 3) * 8;

        const int arow = wr * 64 + (lane & 15);
        const int brow = wc * 64 + (lane & 15);
        const int koff = (lane >> 4) * 8;

        for (int k0 = 0; k0 < K; k0 += 32) {
            __builtin_amdgcn_global_load_lds(
                (const __attribute__((address_space(1))) void*)(A + Abase + (long)r0 * K + k0 + c0),
                (__attribute__((address_space(3))) void*)(Alds + wid * 512), 16, 0, 0);
            __builtin_amdgcn_global_load_lds(
                (const __attribute__((address_space(1))) void*)(A + Abase + (long)r1 * K + k0 + c1),
                (__attribute__((address_space(3))) void*)(Alds + 2048 + wid * 512), 16, 0, 0);
            __builtin_amdgcn_global_load_lds(
                (const __attribute__((address_space(1))) void*)(B + Bbase + (long)r0 * K + k0 + c0),
                (__attribute__((address_space(3))) void*)(Blds + wid * 512), 16, 0, 0);
            __builtin_amdgcn_global_load_lds(
                (const __attribute__((address_space(1))) void*)(B + Bbase + (long)r1 * K + k0 + c1),
                (__attribute__((address_space(3))) void*)(Blds + 2048 + wid * 512), 16, 0, 0);
            __syncthreads();

            bf16x8 af[4], bfr[4];
            #pragma unroll
            for (int m = 0; m < 4; m++)
                af[m] = *reinterpret_cast<const bf16x8*>(&Alds[(arow + m * 16) * 32 + koff]);
            #pragma unroll
            for (int n = 0; n < 4; n++)
                bfr[n] = *reinterpret_cast<const bf16x8*>(&Blds[(brow + n * 16) * 32 + koff]);
            #pragma unroll
            for (int m = 0; m < 4; m++)
                #pragma unroll
                for (int n = 0; n < 4; n++)
                    acc[m][n] = __builtin_amdgcn_mfma_f32_16x16x32_bf16(af[m], bfr[n], acc[m][n], 0, 0, 0);
            __syncthreads();
        }

        const int crow0 = bm * 128 + wr * 64 + ((lane >> 4) << 2);
        const int ccol0 = bn * 128 + wc * 64 + (lane & 15);
        #pragma unroll
        for (int m = 0; m < 4; m++)
            #pragma unroll
            for (int j = 0; j < 4; j++) {
                const long r = crow0 + m * 16 + j;
                #pragma unroll
                for (int n = 0; n < 4; n++)
                    C[r * N + ccol0 + n * 16] = f2bf(acc[m][n][j]);
            }
    } else {
        const int row = blockIdx.x - 256;
        const float4* x4 = reinterpret_cast<const float4*>(x + (long)row * D_MODEL);
        float4 a = x4[t];
        float4 b = x4[256 + t];
        float s  = a.x + a.y + a.z + a.w + b.x + b.y + b.z + b.w;
        float ss = a.x*a.x + a.y*a.y + a.z*a.z + a.w*a.w
                 + b.x*b.x + b.y*b.y + b.z*b.z + b.w*b.w;
        #pragma unroll
        for (int off = 32; off; off >>= 1) {
            s  += __shfl_xor(s, off);
            ss += __shfl_xor(ss, off);
        }
        float* red = reinterpret_cast<float*>(Alds);
        const int lane = t & 63, wid = t >> 6;
        if (lane == 0) { red[wid*2] = s; red[wid*2+1] = ss; }
        __syncthreads();
        s  = red[0] + red[2] + red[4] + red[6];
        ss = red[1] + red[3] + red[5] + red[7];
        const float mean = s * (1.0f / D_MODEL);
        const float var  = ss * (1.0f / D_MODEL) - mean * mean;
        const float inv  = rsqrtf(var + 1e-5f);

        const float4* g4  = reinterpret_cast<const float4*>(gamma);
        const float4* be4 = reinterpret_cast<const float4*>(beta);
        ushort4* h4 = reinterpret_cast<ushort4*>(h + (long)row * D_MODEL);
        {
            float4 g = g4[t], be = be4[t];
            ushort4 o;
            o.x = f2bf((a.x - mean) * inv * g.x + be.x);
            o.y = f2bf((a.y - mean) * inv * g.y + be.y);
            o.z = f2bf((a.z - mean) * inv * g.z + be.z);
            o.w = f2bf((a.w - mean) * inv * g.w + be.w);
            h4[t] = o;
        }
        {
            float4 g = g4[256 + t], be = be4[256 + t];
            ushort4 o;
            o.x = f2bf((b.x - mean) * inv * g.x + be.x);
            o.y = f2bf((b.y - mean) * inv * g.y + be.y);
            o.z = f2bf((b.z - mean) * inv * g.z + be.z);
            o.w = f2bf((b.w - mean) * inv * g.w + be.w);
            h4[256 + t] = o;
        }
    }
}

// ======== K3: big BT-GEMM, 256x256 8-phase (r10/r15 proven best: ~166 us) ========
// C[m][n] = sum_k A[m][k]*B[n][k] + bias[n] + resid[m][n], fp32 out.
// Relaxed intra-phase schedule; one barrier/phase; counted vmcnt(4) at
// ph4/ph8 (never 0 mid-loop); r2-proven swizzle (0 conflicts); LDS-staged
// coalesced epilogue.  Ledger (iter i; tiles 2i,2i+1; stages 2i+1..2i+3):
//   ph1: A1h1(2i+1)   ph2: B1h1(2i+1)   ph3: B0h0(2i+2)   ph4: A0h0(2i+2)+W4
//   ph5: A0h1(2i+2)   ph6: B0h1(2i+2)   ph7: B1h0(2i+3)   ph8: A1h0(2i+3)+W4
#define GLL(src, dst) __builtin_amdgcn_global_load_lds( \
    (const __attribute__((address_space(1))) void*)(src), \
    (__attribute__((address_space(3))) void*)(dst), 16, 0, 0)
#define WAITV4() do { asm volatile("s_waitcnt vmcnt(4)" ::: "memory"); \
                      __builtin_amdgcn_sched_barrier(0); } while (0)
#define WAITV0() do { asm volatile("s_waitcnt vmcnt(0)" ::: "memory"); \
                      __builtin_amdgcn_sched_barrier(0); } while (0)

__global__ __launch_bounds__(512, 2) void gemm_bt_8ph(
    const unsigned short* __restrict__ A, const unsigned short* __restrict__ B,
    float* __restrict__ C, const float* __restrict__ bias,
    const float* __restrict__ resid, int M, int N, int K)
{
    __shared__ __align__(16) char ldsb[131072];

    const int nBN = N >> 8;             // 8
    int wg = blockIdx.x;
    const int cpx = gridDim.x >> 3;     // 512 % 8 == 0
    wg = (wg & 7) * cpx + (wg >> 3);
    const int bm = wg / nBN, bn = wg % nBN;

    const int t = threadIdx.x;
    const int lane = t & 63, wid = t >> 6;
    const int wr = wid >> 2;            // 0..1
    const int wc = wid & 3;             // 0..3

    const long Kl = K;
    const int tr = t >> 3;
    const int c8 = ((t & 7) ^ (tr & 7)) * 8;
    const unsigned short* As = A + (long)(bm * 256 + tr) * Kl + c8;
    const unsigned short* Bs = B + (long)(bn * 256 + tr) * Kl + c8;

#define ST_A(buf, half, kcol) do { \
    const unsigned short* s_ = As + (half) * 128 * Kl + (kcol); \
    char* d_ = ldsb + (buf) * 65536 + (half) * 16384 + t * 16; \
    GLL(s_, d_); GLL(s_ + 64 * Kl, d_ + 8192); } while (0)
#define ST_B(buf, half, kcol) do { \
    const unsigned short* s_ = Bs + (half) * 128 * Kl + (kcol); \
    char* d_ = ldsb + (buf) * 65536 + 32768 + (half) * 16384 + t * 16; \
    GLL(s_, d_); GLL(s_ + 64 * Kl, d_ + 8192); } while (0)

    const int l15 = lane & 15, l4 = lane >> 4;
    const int swz0 = ((l4)     ^ (l15 & 7)) << 4;
    const int swz1 = ((4 + l4) ^ (l15 & 7)) << 4;
    const int aOff = wr * 16384 + l15 * 128;
    const int bOff = 32768 + (wc >> 1) * 16384 + ((wc & 1) * 64 + l15) * 128;

#define LDV(off) (*reinterpret_cast<const bf16x8*>(ldsb + (off)))
#define RD_A(buf, mh) do { \
    _Pragma("unroll") for (int mi = 0; mi < 4; ++mi) \
        af[mi][0] = LDV((buf) * 65536 + aOff + ((mh) * 4 + mi) * 2048 + swz0); \
    _Pragma("unroll") for (int mi = 0; mi < 4; ++mi) \
        af[mi][1] = LDV((buf) * 65536 + aOff + ((mh) * 4 + mi) * 2048 + swz1); } while (0)
#define RD_B0(buf) do { \
    _Pragma("unroll") for (int nj = 0; nj < 2; ++nj) \
        b0[nj][0] = LDV((buf) * 65536 + bOff + nj * 2048 + swz0); \
    _Pragma("unroll") for (int nj = 0; nj < 2; ++nj) \
        b0[nj][1] = LDV((buf) * 65536 + bOff + nj * 2048 + swz1); } while (0)
#define RD_B1(buf) do { \
    _Pragma("unroll") for (int nj = 0; nj < 2; ++nj) \
        b1[nj][0] = LDV((buf) * 65536 + bOff + (2 + nj) * 2048 + swz0); \
    _Pragma("unroll") for (int nj = 0; nj < 2; ++nj) \
        b1[nj][1] = LDV((buf) * 65536 + bOff + (2 + nj) * 2048 + swz1); } while (0)

#define MMQ(mh, nh, BQ) do { \
    __builtin_amdgcn_s_setprio(1); \
    _Pragma("unroll") for (int kk = 0; kk < 2; ++kk) \
    _Pragma("unroll") for (int mi = 0; mi < 4; ++mi) \
    _Pragma("unroll") for (int nj = 0; nj < 2; ++nj) \
        acc[(mh) * 4 + mi][(nh) * 2 + nj] = __builtin_amdgcn_mfma_f32_16x16x32_bf16( \
            af[mi][kk], BQ[nj][kk], acc[(mh) * 4 + mi][(nh) * 2 + nj], 0, 0, 0); \
    __builtin_amdgcn_s_setprio(0); } while (0)
#define ENDP() __builtin_amdgcn_s_barrier()

    bf16x8 af[4][2], b0[2][2], b1[2][2];
    f32x4 acc[8][4];
    #pragma unroll
    for (int i = 0; i < 8; i++)
        #pragma unroll
        for (int j = 0; j < 4; j++) acc[i][j] = (f32x4){0.f, 0.f, 0.f, 0.f};

    const int NI = K >> 7;              // 16 iterations, 2 K-tiles each

    ST_A(0, 0, 0); ST_A(0, 1, 0); ST_B(0, 0, 0); ST_B(0, 1, 0);
    ST_B(1, 0, 64); ST_A(1, 0, 64);
    WAITV4();
    __builtin_amdgcn_s_barrier();

    for (int i = 0; i < NI; ++i) {
        const int kcA1 = (i << 7) + 64;
        const int kcN0 = (i << 7) + 128;
        const int kcN1 = (i << 7) + 192;
        const bool more = (i + 1 < NI);

        RD_A(0, 0); RD_B0(0);
        ST_A(1, 1, kcA1);
        MMQ(0, 0, b0); ENDP();

        RD_B1(0);
        ST_B(1, 1, kcA1);
        MMQ(0, 1, b1); ENDP();

        RD_A(0, 1);
        if (more) ST_B(0, 0, kcN0);
        MMQ(1, 0, b0); ENDP();

        if (more) ST_A(0, 0, kcN0);
        MMQ(1, 1, b1);
        if (more) { WAITV4(); } else { WAITV0(); }
        ENDP();

        RD_A(1, 0); RD_B0(1);
        if (more) ST_A(0, 1, kcN0);
        MMQ(0, 0, b0); ENDP();

        RD_B1(1);
        if (more) ST_B(0, 1, kcN0);
        MMQ(0, 1, b1); ENDP();

        RD_A(1, 1);
        if (more) ST_B(1, 0, kcN1);
        MMQ(1, 0, b0); ENDP();

        if (more) ST_A(1, 0, kcN1);
        MMQ(1, 1, b1);
        if (more) { WAITV4(); }
        ENDP();
    }
#undef ST_A
#undef ST_B
#undef RD_A
#undef RD_B0
#undef RD_B1
#undef MMQ
#undef ENDP
#undef LDV

    // ---- epilogue: LDS-staged, fully-coalesced stores ----
    float* ldsf = reinterpret_cast<float*>(ldsb);
    float bias4[4];
    #pragma unroll
    for (int n = 0; n < 4; n++)
        bias4[n] = bias[bn * 256 + wc * 64 + l15 + n * 16];
    const int wcol = wc * 64 + l15;

    #pragma unroll
    for (int rd = 0; rd < 4; ++rd) {
        __syncthreads();
        if (wr == (rd >> 1)) {
            #pragma unroll
            for (int mm = 0; mm < 4; ++mm) {
                const int m = (rd & 1) * 4 + mm;
                #pragma unroll
                for (int j = 0; j < 4; ++j) {
                    const int rl = mm * 16 + l4 * 4 + j;
                    #pragma unroll
                    for (int n = 0; n < 4; ++n)
                        ldsf[rl * 260 + wcol + n * 16] = acc[m][n][j] + bias4[n];
                }
            }
        }
        __syncthreads();
        const long gr0 = (long)bm * 256 + rd * 64;
        #pragma unroll
        for (int rr = 0; rr < 8; ++rr) {
            const int rl = wid * 8 + rr;
            const long go = (gr0 + rl) * N + bn * 256 + lane * 4;
            float4 v = *reinterpret_cast<const float4*>(&ldsf[rl * 260 + lane * 4]);
            const float4 rv = *reinterpret_cast<const float4*>(&resid[go]);
            v.x += rv.x; v.y += rv.y; v.z += rv.z; v.w += rv.w;
            *reinterpret_cast<float4*>(&C[go]) = v;
        }
    }
}

extern "C" void kernel_launch(void* const* d_in, const int* in_sizes, int n_in,
                              void* d_out, int out_size, void* d_ws, size_t ws_size,
                              hipStream_t stream) {
    // setup_inputs order: x, w_q, b_q, w_k, b_k, w_v, b_v, w_o, b_o, ln_gamma, ln_beta
    const float* x     = (const float*)d_in[0];
    const float* w_v   = (const float*)d_in[5];
    const float* b_v   = (const float*)d_in[6];
    const float* w_o   = (const float*)d_in[7];
    const float* b_o   = (const float*)d_in[8];
    const float* gamma = (const float*)d_in[9];
    const float* beta  = (const float*)d_in[10];
    float* out = (float*)d_out;

    char* ws = (char*)d_ws;
    unsigned short* h   = (unsigned short*)(ws);                              // 64 MiB
    unsigned short* wvT = (unsigned short*)(ws + 67108864L);                  // 8 MiB
    unsigned short* woB = (unsigned short*)(ws + 67108864L + 8388608L);       // 8 MiB
    unsigned short* Wc  = (unsigned short*)(ws + 67108864L + 2 * 8388608L);   // 8 MiB
    float*          b_c = (float*)(ws + 67108864L + 3 * 8388608L);            // 8 KiB

    // K1: transpose(w_v) || {convert(w_o) + bias dot, single w_o pass}
    prep_kernel<<<6144, 256, 0, stream>>>(w_v, w_o, b_v, b_o, wvT, woB, b_c);
    // K2: Wc = woB . wvT^T (blocks 0-255) || h = LN(x) (blocks 256+)
    lnwc_kernel<<<256 + N_BATCH, 256, 0, stream>>>(woB, wvT, Wc, x, gamma, beta, h);
    // K3: out = h . Wc^T + b_c + x
    gemm_bt_8ph<<<(N_BATCH / 256) * (D_MODEL / 256), 512, 0, stream>>>(
        h, Wc, out, b_c, x, N_BATCH, D_MODEL, D_MODEL);
}